// Round 1
// 717.692 us; speedup vs baseline: 1.9169x; 1.9169x over previous
//
#include <hip/hip_runtime.h>
#include <hip/hip_bf16.h>
#include <hip/hip_fp16.h>

#define VOCAB 5000
#define EMB 128
#define H1D 128
#define H2D 64
#define QD 64
#define TDIM 256
#define BDIM 512
#define LTEXT 30
#define LSTEPS 29

typedef __attribute__((ext_vector_type(4))) float f32x4;
typedef __attribute__((ext_vector_type(8))) _Float16 f16x8;
typedef __attribute__((ext_vector_type(2))) _Float16 h2v;

// ---- workspace layout (bytes) ----
#define OFF_WOUT  0u                    // 5000*128 fp16 = 1,280,000
#define OFF_W1H   0x140000u             // 512*320 fp16  =   327,680
#define OFF_W2H   (OFF_W1H + 512u*320u*2u)
#define OFF_WQH   (OFF_W2H + 256u*192u*2u)
#define OFF_B1    (OFF_WQH + 64u*64u*2u)
#define OFF_B2    (OFF_B1 + 512u*4u)
#define OFF_H2CTX 0x1B0000u             // 14848*128 fp16 = 3,801,088

__device__ __forceinline__ float sigmoidf_(float x) {
    return 1.0f / (1.0f + __expf(-x));
}

__device__ __forceinline__ float dot8(f16x8 w, f16x8 u, float acc) {
    union U8 { f16x8 v; h2v h[4]; };
    U8 W; W.v = w; U8 X; X.v = u;
#if __has_builtin(__builtin_amdgcn_fdot2)
    acc = __builtin_amdgcn_fdot2(W.h[0], X.h[0], acc, false);
    acc = __builtin_amdgcn_fdot2(W.h[1], X.h[1], acc, false);
    acc = __builtin_amdgcn_fdot2(W.h[2], X.h[2], acc, false);
    acc = __builtin_amdgcn_fdot2(W.h[3], X.h[3], acc, false);
#else
    #pragma unroll
    for (int i = 0; i < 8; ++i) acc += (float)w[i] * (float)u[i];
#endif
    return acc;
}

// ---------------------------------------------------------------------------
// Prep kernels: pack weights to fp16, fold biases. (unchanged)
// ---------------------------------------------------------------------------
__global__ void k_cvt_f16(const float* __restrict__ W, _Float16* __restrict__ Wh, int n) {
    int i = blockIdx.x * 256 + threadIdx.x;
    if (i < n) Wh[i] = (_Float16)W[i];
}

__global__ void k_prep_w1(const float* __restrict__ Wih1, const float* __restrict__ Whh1,
                          const float* __restrict__ bih1, const float* __restrict__ bhh1,
                          _Float16* __restrict__ W1h, float* __restrict__ bias1) {
    int g = blockIdx.x;          // 512
    int k = threadIdx.x;         // 320
    float v = (k < 192) ? Wih1[g * 192 + k] : Whh1[g * 128 + (k - 192)];
    W1h[g * 320 + k] = (_Float16)v;
    if (k == 0) bias1[g] = bih1[g] + bhh1[g];
}

__global__ void k_prep_w2(const float* __restrict__ Wih2, const float* __restrict__ Whh2,
                          const float* __restrict__ bih2, const float* __restrict__ bhh2,
                          _Float16* __restrict__ W2h, float* __restrict__ bias2) {
    int g = blockIdx.x;          // 256
    int k = threadIdx.x;         // 192
    float v = (k < 128) ? Wih2[g * 128 + k] : Whh2[g * 64 + (k - 128)];
    W2h[g * 192 + k] = (_Float16)v;
    if (k == 0) bias2[g] = bih2[g] + bhh2[g];
}

// ---------------------------------------------------------------------------
// Kernel A v3: 256 blocks x 512 threads, 2 rows/block.
// Step loop touches NO global memory except h2ctx stores + emb prefetch:
//   - W1 rows live in VGPRs (160/thread, loaded once)
//   - key (fp16, XOR-swizzled) and values (fp16, transposed [v][t], swizzled)
//     preloaded to LDS once (step-invariant data)
//   - Wq in LDS (swizzled); biases/c1/c2 thread-stationary in registers
//   - next-step embedding prefetched into an LDS ring (latency hidden)
// ---------------------------------------------------------------------------
__global__ __launch_bounds__(512, 2) void k_recurrent(
    const float* __restrict__ key, const float* __restrict__ values,
    const float* __restrict__ mask, const int* __restrict__ text,
    const float* __restrict__ emb,
    const _Float16* __restrict__ W1h, const float* __restrict__ bias1,
    const _Float16* __restrict__ W2h, const float* __restrict__ bias2,
    const _Float16* __restrict__ Wqh, const float* __restrict__ bq,
    _Float16* __restrict__ h2ctx)
{
    // ---- LDS (~154 KB of 160 KB/CU) ----
    __shared__ alignas(16) _Float16 s_key16[2 * 256 * 64];  // [r][t][k], 8 slots/row, slot^=(t&7)
    __shared__ alignas(16) _Float16 s_valT [2 * 64 * 256];  // [r][v][t], 32 slots/row, slot^=(v&31)
    __shared__ alignas(16) _Float16 s_x16[2][2][128];       // emb ring buffer
    __shared__ alignas(16) _Float16 s_Wq[64 * 64];          // 8 slots/row, slot^=(qj&7)
    __shared__ alignas(16) _Float16 s_v16[2][192];          // [h1(128) | h2(64)] fp16
    __shared__ alignas(16) _Float16 s_ctx16[2][64];
    __shared__ alignas(16) _Float16 s_q16[2][64];
    __shared__ alignas(16) _Float16 s_ma16[2 * 256];
    __shared__ _Float16 s_mask16[2 * 256];
    __shared__ float s_g1[2][512];
    __shared__ float s_g2p[2][2][256];                      // [half][r][gate]
    __shared__ float s_cp[2][4][64];
    __shared__ float s_redM[8], s_redA[8], s_redB[8];
    __shared__ int   s_tok[2][LSTEPS];

    const int tid = threadIdx.x;
    const int b0 = blockIdx.x * 2;

    // ---- W1 gate-row into registers (160 VGPRs) ----
    f16x8 w1[40];
    {
        const f16x8* w1g = (const f16x8*)(W1h + (size_t)tid * 320);
        #pragma unroll
        for (int c = 0; c < 40; ++c) w1[c] = w1g[c];
    }
    const float bias1r = bias1[tid];
    const float bias2r = (tid < 256) ? bias2[tid] : 0.f;   // half==0 adds bias once
    const float bqr    = (tid < 128) ? bq[tid & 63] : 0.f;

    // ---- one-time preload ----
    if (tid < 64) {
        int r = tid >> 5, tt = tid & 31;
        if (tt < LSTEPS) s_tok[r][tt] = text[(b0 + r) * LTEXT + tt];
    }
    if (tid < 256) {                                        // x for t=0
        int r = tid >> 7, k = tid & 127;
        int tok = text[(b0 + r) * LTEXT];
        s_x16[0][r][k] = (_Float16)emb[(size_t)tok * EMB + k];
    }
    {                                                       // Wq swizzled
        int qj = tid >> 3, c = tid & 7;
        f16x8 w = *(const f16x8*)(Wqh + (qj << 6) + (c << 3));
        *(f16x8*)&s_Wq[(qj << 6) + (((c ^ (qj & 7))) << 3)] = w;
    }
    {                                                       // mask (fp16 exact for 0/1)
        int r = tid >> 8, tk = tid & 255;
        s_mask16[tid] = (_Float16)mask[(size_t)(b0 + r) * TDIM + tk];
    }
    if (tid < 384) ((_Float16*)s_v16)[tid] = (_Float16)0.f; // h1,h2 = 0
    if (tid < 128) ((_Float16*)s_ctx16)[tid] = (_Float16)0.f;

    // key/values -> LDS fp16 swizzled; coalesced global reads (512B per t)
    {
        const int tq  = tid >> 7;            // 0..3 (4 t per iter)
        const int idx = tid & 127;
        const int r = idx >> 6, kk = idx & 63;
        #pragma unroll 4
        for (int it = 0; it < 64; ++it) {
            int t = (it << 2) + tq;
            size_t g = ((size_t)t * BDIM + b0 + r) * QD + kk;
            float kf = key[g];
            float vf = values[g];
            s_key16[(((r << 8) + t) << 6) + ((((kk >> 3) ^ (t & 7))) << 3) + (kk & 7)] = (_Float16)kf;
            s_valT [(((r << 6) + kk) << 8) + ((((t >> 3) ^ (kk & 31))) << 3) + (t & 7)] = (_Float16)vf;
        }
    }

    float c1reg = 0.f;   // c1 state for tid<256 (r=tid>>7, j=tid&127)
    float c2reg = 0.f;   // c2 state for tid<128 (r=tid>>6, j=tid&63)
    __syncthreads();

    #pragma unroll 1
    for (int t = 0; t < LSTEPS; ++t) {
        // ---- prefetch next step's embedding (issue load now, write late) ----
        float xpref = 0.f;
        const int pr = tid >> 7, pk = tid & 127;
        const bool havepref = (t + 1 < LSTEPS) && (tid < 256);
        if (havepref) {
            int tok = s_tok[pr][t + 1];
            xpref = emb[(size_t)tok * EMB + pk];
        }

        // ---- (b) g1: thread = gate, both rows; weights in VGPRs, u via LDS broadcast ----
        {
            const f16x8* xc0 = (const f16x8*)&s_x16[t & 1][0][0];
            const f16x8* xc1 = (const f16x8*)&s_x16[t & 1][1][0];
            const f16x8* cc0 = (const f16x8*)&s_ctx16[0][0];
            const f16x8* cc1 = (const f16x8*)&s_ctx16[1][0];
            const f16x8* hh0 = (const f16x8*)&s_v16[0][0];
            const f16x8* hh1 = (const f16x8*)&s_v16[1][0];
            float a0 = bias1r, a1 = bias1r;
            #pragma unroll
            for (int c = 0; c < 16; ++c) { f16x8 w = w1[c];      a0 = dot8(w, xc0[c], a0); a1 = dot8(w, xc1[c], a1); }
            #pragma unroll
            for (int c = 0; c < 8;  ++c) { f16x8 w = w1[16 + c]; a0 = dot8(w, cc0[c], a0); a1 = dot8(w, cc1[c], a1); }
            #pragma unroll
            for (int c = 0; c < 16; ++c) { f16x8 w = w1[24 + c]; a0 = dot8(w, hh0[c], a0); a1 = dot8(w, hh1[c], a1); }
            s_g1[0][tid] = a0;
            s_g1[1][tid] = a1;
        }
        __syncthreads();

        // ---- (c) LSTM1 (256 units), c1 in register ----
        if (tid < 256) {
            int r = tid >> 7, j = tid & 127;
            float gi = s_g1[r][j], gf = s_g1[r][128 + j];
            float gg = s_g1[r][256 + j], go = s_g1[r][384 + j];
            float c = sigmoidf_(gf) * c1reg + sigmoidf_(gi) * tanhf(gg);
            c1reg = c;
            float h = sigmoidf_(go) * tanhf(c);
            s_v16[r][j] = (_Float16)h;
        }
        __syncthreads();

        // ---- (d) g2: thread = (gate=tid&255, half=tid>>8), partials for both rows ----
        {
            const int g = tid & 255, half = tid >> 8;
            const f16x8* wrow = (const f16x8*)(W2h + (size_t)g * 192 + half * 96);
            const f16x8* v0 = (const f16x8*)&s_v16[0][0] + half * 12;
            const f16x8* v1 = (const f16x8*)&s_v16[1][0] + half * 12;
            float p0 = bias2r, p1 = bias2r;
            #pragma unroll
            for (int c = 0; c < 12; ++c) {
                f16x8 w = wrow[c];
                p0 = dot8(w, v0[c], p0);
                p1 = dot8(w, v1[c], p1);
            }
            s_g2p[half][0][g] = p0;
            s_g2p[half][1][g] = p1;
        }
        __syncthreads();

        // ---- (e) LSTM2 (128 units), c2 in register; store h2 ----
        if (tid < 128) {
            int r = tid >> 6, j = tid & 63;
            float gi = s_g2p[0][r][j]       + s_g2p[1][r][j];
            float gf = s_g2p[0][r][64 + j]  + s_g2p[1][r][64 + j];
            float gg = s_g2p[0][r][128 + j] + s_g2p[1][r][128 + j];
            float go = s_g2p[0][r][192 + j] + s_g2p[1][r][192 + j];
            float c = sigmoidf_(gf) * c2reg + sigmoidf_(gi) * tanhf(gg);
            c2reg = c;
            float h = sigmoidf_(go) * tanhf(c);
            s_v16[r][128 + j] = (_Float16)h;
            h2ctx[((size_t)(b0 + r) * LSTEPS + t) * 128 + j] = (_Float16)h;
        }
        __syncthreads();

        // ---- (f) q = Wq @ h2 + bq (Wq from swizzled LDS) ----
        if (tid < 128) {
            int r = tid >> 6, qj = tid & 63;
            const f16x8* hv = (const f16x8*)&s_v16[r][128];
            float a = bqr;
            #pragma unroll
            for (int c = 0; c < 8; ++c) {
                f16x8 w = *(const f16x8*)&s_Wq[(qj << 6) + (((c ^ (qj & 7))) << 3)];
                a = dot8(w, hv[c], a);
            }
            s_q16[r][qj] = (_Float16)a;
        }
        __syncthreads();

        // ---- (g) energies from LDS key (fp16) + (h) softmax ----
        const int row = tid >> 8, tk = tid & 255;
        {
            const _Float16* kb = s_key16 + (((row << 8) + tk) << 6);
            const f16x8* qv = (const f16x8*)&s_q16[row][0];
            float e = 0.f;
            #pragma unroll
            for (int j = 0; j < 8; ++j) {
                f16x8 kk = *(const f16x8*)(kb + (((j ^ (tk & 7))) << 3));
                e = dot8(kk, qv[j], e);
            }
            const int wave = tid >> 6, lane = tid & 63;
            float m = e;
            #pragma unroll
            for (int off = 1; off < 64; off <<= 1) m = fmaxf(m, __shfl_xor(m, off));
            if (lane == 0) s_redM[wave] = m;
            __syncthreads();
            float mrow = fmaxf(fmaxf(s_redM[row * 4], s_redM[row * 4 + 1]),
                               fmaxf(s_redM[row * 4 + 2], s_redM[row * 4 + 3]));
            float p = __expf(e - mrow);
            float mp = (float)s_mask16[(row << 8) + tk] * p;
            float sp = p, smp = mp;
            #pragma unroll
            for (int off = 1; off < 64; off <<= 1) {
                sp += __shfl_xor(sp, off);
                smp += __shfl_xor(smp, off);
            }
            if (lane == 0) { s_redA[wave] = sp; s_redB[wave] = smp; }
            __syncthreads();
            float s1 = s_redA[row * 4] + s_redA[row * 4 + 1] + s_redA[row * 4 + 2] + s_redA[row * 4 + 3];
            float S2 = s_redB[row * 4] + s_redB[row * 4 + 1] + s_redB[row * 4 + 2] + s_redB[row * 4 + 3];
            float denom = fmaxf(S2, 2e-30f * s1);
            s_ma16[(row << 8) + tk] = (_Float16)(mp / denom);
        }
        __syncthreads();

        // ---- (i) ctx from transposed LDS values (fp16 dot) ----
        {
            const int v = tid & 63, ch = (tid >> 6) & 3;
            const _Float16* vb = s_valT + (((row << 6) + v) << 8);
            const f16x8* mac = (const f16x8*)&s_ma16[(row << 8) + (ch << 6)];
            float acc = 0.f;
            #pragma unroll
            for (int j = 0; j < 8; ++j) {
                int s = ch * 8 + j;
                f16x8 vv = *(const f16x8*)(vb + (((s ^ (v & 31))) << 3));
                acc = dot8(vv, mac[j], acc);
            }
            s_cp[row][ch][v] = acc;
        }
        // late half of the emb prefetch (global latency now hidden)
        if (havepref) s_x16[(t + 1) & 1][pr][pk] = (_Float16)xpref;
        __syncthreads();
        if (tid < 128) {
            int r = tid >> 6, v = tid & 63;
            float c = s_cp[r][0][v] + s_cp[r][1][v] + s_cp[r][2][v] + s_cp[r][3][v];
            s_ctx16[r][v] = (_Float16)c;
            h2ctx[((size_t)(b0 + r) * LSTEPS + t) * 128 + 64 + v] = (_Float16)c;
        }
        __syncthreads();
    }
}

// ---------------------------------------------------------------------------
// Kernel B: out = h2ctx @ W_out^T + b_out, fp16 MFMA 16x16x32. (unchanged)
// M = 14848, N = 5000, K = 128. 64x64 tile, 4 waves.
// ---------------------------------------------------------------------------
#define KP 136

__global__ __launch_bounds__(256) void k_outproj(
    const _Float16* __restrict__ A,
    const _Float16* __restrict__ Bw,
    const float* __restrict__ b_out,
    float* __restrict__ out)
{
    __shared__ _Float16 As[64 * KP];
    __shared__ _Float16 Bs[64 * KP];
    const int tid = threadIdx.x;
    const int m0 = blockIdx.y * 64;
    const int v0 = blockIdx.x * 64;

    const uint4* Ag = (const uint4*)(A + (size_t)m0 * 128);
    uint4* AsU = (uint4*)As;
    #pragma unroll
    for (int i = 0; i < 4; ++i) {
        int fi = tid + 256 * i;
        int r = fi >> 4, c = fi & 15;
        AsU[r * 17 + c] = Ag[fi];
    }
    const uint4* Bg = (const uint4*)Bw;
    uint4* BsU = (uint4*)Bs;
    #pragma unroll
    for (int i = 0; i < 4; ++i) {
        int fi = tid + 256 * i;
        int r = fi >> 4, c = fi & 15;
        int v = v0 + r;
        uint4 val = make_uint4(0u, 0u, 0u, 0u);
        if (v < VOCAB) val = Bg[(size_t)v * 16 + c];
        BsU[r * 17 + c] = val;
    }
    __syncthreads();

    const int wv = tid >> 6, lane = tid & 63;
    const int fm = lane & 15, quad = lane >> 4;

    f32x4 acc[4];
    #pragma unroll
    for (int nt = 0; nt < 4; ++nt) acc[nt] = (f32x4){0.f, 0.f, 0.f, 0.f};

    #pragma unroll
    for (int kt = 0; kt < 4; ++kt) {
        f16x8 af = *(const f16x8*)&As[(16 * wv + fm) * KP + kt * 32 + quad * 8];
        #pragma unroll
        for (int nt = 0; nt < 4; ++nt) {
            f16x8 bf = *(const f16x8*)&Bs[(nt * 16 + fm) * KP + kt * 32 + quad * 8];
            acc[nt] = __builtin_amdgcn_mfma_f32_16x16x32_f16(af, bf, acc[nt], 0, 0, 0);
        }
    }

    #pragma unroll
    for (int nt = 0; nt < 4; ++nt) {
        int v = v0 + nt * 16 + fm;
        if (v < VOCAB) {
            float bo = b_out[v];
            #pragma unroll
            for (int r = 0; r < 4; ++r) {
                int rowm = m0 + 16 * wv + quad * 4 + r;
                out[(size_t)rowm * VOCAB + v] = acc[nt][r] + bo;
            }
        }
    }
}

extern "C" void kernel_launch(void* const* d_in, const int* in_sizes, int n_in,
                              void* d_out, int out_size, void* d_ws, size_t ws_size,
                              hipStream_t stream) {
    const float* key    = (const float*)d_in[0];
    const float* values = (const float*)d_in[1];
    const float* mask   = (const float*)d_in[2];
    const int*   text   = (const int*)d_in[3];
    const float* emb    = (const float*)d_in[4];
    const float* Wih1   = (const float*)d_in[5];
    const float* Whh1   = (const float*)d_in[6];
    const float* bih1   = (const float*)d_in[7];
    const float* bhh1   = (const float*)d_in[8];
    const float* Wih2   = (const float*)d_in[9];
    const float* Whh2   = (const float*)d_in[10];
    const float* bih2   = (const float*)d_in[11];
    const float* bhh2   = (const float*)d_in[12];
    const float* Wq     = (const float*)d_in[13];
    const float* bq     = (const float*)d_in[14];
    const float* Wout   = (const float*)d_in[15];
    const float* bout   = (const float*)d_in[16];
    float* out = (float*)d_out;

    char* ws = (char*)d_ws;
    _Float16* WoutH = (_Float16*)(ws + OFF_WOUT);
    _Float16* W1h   = (_Float16*)(ws + OFF_W1H);
    _Float16* W2h   = (_Float16*)(ws + OFF_W2H);
    _Float16* Wqh   = (_Float16*)(ws + OFF_WQH);
    float*    bias1 = (float*)(ws + OFF_B1);
    float*    bias2 = (float*)(ws + OFF_B2);
    _Float16* h2ctx = (_Float16*)(ws + OFF_H2CTX);

    k_cvt_f16<<<dim3((VOCAB * EMB + 255) / 256), dim3(256), 0, stream>>>(Wout, WoutH, VOCAB * EMB);
    k_cvt_f16<<<dim3(16), dim3(256), 0, stream>>>(Wq, Wqh, QD * H2D);
    k_prep_w1<<<dim3(512), dim3(320), 0, stream>>>(Wih1, Whh1, bih1, bhh1, W1h, bias1);
    k_prep_w2<<<dim3(256), dim3(192), 0, stream>>>(Wih2, Whh2, bih2, bhh2, W2h, bias2);

    k_recurrent<<<dim3(BDIM / 2), dim3(512), 0, stream>>>(
        key, values, mask, text, emb, W1h, bias1, W2h, bias2, Wqh, bq, h2ctx);

    k_outproj<<<dim3((VOCAB + 63) / 64, (BDIM * LSTEPS) / 64), dim3(256), 0, stream>>>(
        h2ctx, WoutH, bout, out);
}